// Round 1
// baseline (245.053 us; speedup 1.0000x reference)
//
#include <hip/hip_runtime.h>

#define N_ROWS   131072
#define D_IN     256
#define D_MID    128
#define N_SUBS   64

// ws layout: rowsum[N_ROWS] floats | gsum[64] | gcnt[64]

// One wave (64 lanes) per row: lane l loads float4 at col 4l..4l+3 (fully
// coalesced 1 KiB/wave), tree-reduce across the wave, lane 0 stores rowsum.
// Block 0 additionally zeroes the 128 group bins (consumed only by k2, which
// runs after this kernel completes -> no race).
__global__ __launch_bounds__(256) void k1_rowsum(const float* __restrict__ x,
                                                 float* __restrict__ rowsum,
                                                 float* __restrict__ bins) {
    if (blockIdx.x == 0 && threadIdx.x < 2 * N_SUBS) bins[threadIdx.x] = 0.0f;
    int row  = blockIdx.x * 4 + (threadIdx.x >> 6);
    int lane = threadIdx.x & 63;
    const float4* xr = (const float4*)(x + (size_t)row * D_IN);
    float4 v = xr[lane];
    float s = (v.x + v.y) + (v.z + v.w);
    #pragma unroll
    for (int m = 32; m >= 1; m >>= 1) s += __shfl_xor(s, m, 64);
    if (lane == 0) rowsum[row] = s;
}

// 64 blocks grid-stride over rows; LDS 64-bin accumulate (shared atomics),
// then one global atomicAdd per bin per block (64x64 = 4096 atomics total).
__global__ __launch_bounds__(256) void k2_group(const float* __restrict__ rowsum,
                                                const int* __restrict__ sub,
                                                float* __restrict__ gsum,
                                                float* __restrict__ gcnt) {
    __shared__ float ls[N_SUBS];
    __shared__ float lc[N_SUBS];
    if (threadIdx.x < N_SUBS) { ls[threadIdx.x] = 0.0f; lc[threadIdx.x] = 0.0f; }
    __syncthreads();
    int stride = gridDim.x * blockDim.x;
    for (int i = blockIdx.x * blockDim.x + threadIdx.x; i < N_ROWS; i += stride) {
        int g = sub[i];
        atomicAdd(&ls[g], rowsum[i]);
        atomicAdd(&lc[g], 1.0f);
    }
    __syncthreads();
    if (threadIdx.x < N_SUBS) {
        atomicAdd(&gsum[threadIdx.x], ls[threadIdx.x]);
        atomicAdd(&gcnt[threadIdx.x], lc[threadIdx.x]);
    }
}

// One wave per row: o = relu(Lambda*(rowsum[i] + D_MID * s[sub[i]])),
// s[g] = relu(Gamma * (cnt>0 ? gsum/cnt : rowsum[0])). Write 64 float4 of o.
__global__ __launch_bounds__(256) void k3_out(const float* __restrict__ rowsum,
                                              const int* __restrict__ sub,
                                              const float* __restrict__ gsum,
                                              const float* __restrict__ gcnt,
                                              const float* __restrict__ Gamma,
                                              const float* __restrict__ Lambda,
                                              float* __restrict__ out) {
    int row  = blockIdx.x * 4 + (threadIdx.x >> 6);
    int lane = threadIdx.x & 63;
    int g = sub[row];
    float c = gcnt[g];
    float meansum = (c > 0.0f) ? (gsum[g] / c) : rowsum[0];   // empty-group fallback: mean over x[0]
    float s = Gamma[0] * meansum;
    s = s > 0.0f ? s : 0.0f;                                  // relu
    float o = Lambda[0] * (rowsum[row] + (float)D_MID * s);
    o = o > 0.0f ? o : 0.0f;                                  // relu
    float4 v = make_float4(o, o, o, o);
    ((float4*)(out + (size_t)row * D_IN))[lane] = v;          // OUTPUT_DIMS == 256
}

extern "C" void kernel_launch(void* const* d_in, const int* in_sizes, int n_in,
                              void* d_out, int out_size, void* d_ws, size_t ws_size,
                              hipStream_t stream) {
    const float* x      = (const float*)d_in[0];
    const int*   sub    = (const int*)d_in[1];
    const float* Gamma  = (const float*)d_in[2];
    const float* Lambda = (const float*)d_in[3];
    float* out = (float*)d_out;

    float* rowsum = (float*)d_ws;            // N_ROWS floats
    float* gsum   = rowsum + N_ROWS;         // 64 floats
    float* gcnt   = gsum + N_SUBS;           // 64 floats

    k1_rowsum<<<N_ROWS / 4, 256, 0, stream>>>(x, rowsum, gsum);
    k2_group<<<64, 256, 0, stream>>>(rowsum, sub, gsum, gcnt);
    k3_out<<<N_ROWS / 4, 256, 0, stream>>>(rowsum, sub, gsum, gcnt, Gamma, Lambda, out);
}